// Round 3
// baseline (182.383 us; speedup 1.0000x reference)
//
#include <hip/hip_runtime.h>
#include <math.h>

#define NEG_INF -1e9f

// K1: s[e] = dot(edge_emb[e], W)   -- one wave (64 lanes) per 256-float row.
// Memory-floor kernel: reads emb exactly once (102.4 MB), coalesced float4.
__global__ __launch_bounds__(256) void k_edge_dot(
    const float* __restrict__ emb, const float* __restrict__ W,
    float* __restrict__ s, int n_edges)
{
    int wave = (blockIdx.x * (int)blockDim.x + (int)threadIdx.x) >> 6;
    int lane = threadIdx.x & 63;
    if (wave >= n_edges) return;
    const float4 e = ((const float4*)emb)[wave * 64 + lane];
    const float4 w = ((const float4*)W)[lane];
    float d = e.x * w.x + e.y * w.y + e.z * w.z + e.w * w.w;
#pragma unroll
    for (int off = 32; off; off >>= 1) d += __shfl_down(d, off, 64);
    if (lane == 0) s[wave] = d;
}

// K2 fused with finalize (last-block pattern):
//  - per-path logits with mask short-circuit (no gathers for masked paths)
//  - last block to finish runs argmax + logsumexp + z[p] materialization.
__global__ __launch_bounds__(256) void k_logits_final(
    const float* __restrict__ s, const int* __restrict__ paths,
    const int* __restrict__ path_lens, const int* __restrict__ path_mask,
    const float* __restrict__ b, const float* __restrict__ emb,
    float* __restrict__ logits, int* __restrict__ counter,
    float* __restrict__ out, int n_paths, int max_len)
{
    int tid = threadIdx.x;
    int p = blockIdx.x * 256 + tid;
    if (p < n_paths) {
        if (path_mask[p] == 0) {
            logits[p] = NEG_INF;                 // skip gathers entirely
        } else {
            int len = path_lens[p] + 1;          // 1..16
            const int* pp = paths + (size_t)p * max_len;
            float acc = 0.f;
            if (max_len == 16) {
                const int4* pp4 = (const int4*)pp;
                int4 a0 = pp4[0], a1 = pp4[1], a2 = pp4[2], a3 = pp4[3];
                int idx[16] = { a0.x, a0.y, a0.z, a0.w, a1.x, a1.y, a1.z, a1.w,
                                a2.x, a2.y, a2.z, a2.w, a3.x, a3.y, a3.z, a3.w };
#pragma unroll
                for (int j = 0; j < 16; ++j) {
                    float v = s[idx[j]];         // always in-bounds
                    acc += (j < len) ? v : 0.f;
                }
            } else {
                for (int j = 0; j < len; ++j) acc += s[pp[j]];
            }
            logits[p] = acc / (float)len + b[0];
        }
    }

    // ---- last-block handshake ----
    __shared__ int s_last;
    __threadfence();                             // flush logits to device scope
    __syncthreads();
    if (tid == 0) {
        int prev = atomicAdd(counter, 1);        // device-scope by default
        s_last = (prev == (int)gridDim.x - 1);
    }
    __syncthreads();
    if (!s_last) return;
    __threadfence();                             // acquire: invalidate caches

    // ---- finalize (single block, 256 threads = 4 waves) ----
    __shared__ float sv[4];
    __shared__ int   si[4];
    __shared__ float ssum[4];
    __shared__ int   s_p, s_len;
    __shared__ float s_max, s_logprob;

    int lane = tid & 63, wv = tid >> 6;
    int n4 = n_paths >> 2;
    const float4* l4 = (const float4*)logits;

    // pass 1: argmax with first-index tie-break
    float bv = -INFINITY; int bi = 0x7fffffff;
    for (int i = tid; i < n4; i += 256) {
        float4 v = l4[i];
        int base = i << 2;
        if (v.x > bv) { bv = v.x; bi = base; }
        if (v.y > bv) { bv = v.y; bi = base + 1; }
        if (v.z > bv) { bv = v.z; bi = base + 2; }
        if (v.w > bv) { bv = v.w; bi = base + 3; }
    }
    for (int i = (n4 << 2) + tid; i < n_paths; i += 256) {
        float v = logits[i];
        if (v > bv) { bv = v; bi = i; }
    }
#pragma unroll
    for (int off = 32; off; off >>= 1) {
        float ov = __shfl_down(bv, off, 64);
        int   oi = __shfl_down(bi, off, 64);
        if (ov > bv || (ov == bv && oi < bi)) { bv = ov; bi = oi; }
    }
    if (lane == 0) { sv[wv] = bv; si[wv] = bi; }
    __syncthreads();
    if (tid == 0) {
        float mv = sv[0]; int mi = si[0];
        for (int w = 1; w < 4; ++w)
            if (sv[w] > mv || (sv[w] == mv && si[w] < mi)) { mv = sv[w]; mi = si[w]; }
        s_max = mv; s_p = mi; s_len = path_lens[mi] + 1;
    }
    __syncthreads();
    float mx = s_max;

    // pass 2: logsumexp; logp[argmax] = -log(sum exp(l - max))
    float se = 0.f;
    for (int i = tid; i < n4; i += 256) {
        float4 v = l4[i];
        se += expf(v.x - mx) + expf(v.y - mx) + expf(v.z - mx) + expf(v.w - mx);
    }
    for (int i = (n4 << 2) + tid; i < n_paths; i += 256)
        se += expf(logits[i] - mx);
#pragma unroll
    for (int off = 32; off; off >>= 1) se += __shfl_down(se, off, 64);
    if (lane == 0) ssum[wv] = se;
    __syncthreads();
    if (tid == 0) {
        float t = ssum[0] + ssum[1] + ssum[2] + ssum[3];
        s_logprob = -logf(t);
    }
    __syncthreads();

    // z[p]: 256 threads, one per hidden dim; mean over winner's valid edges
    int p2 = s_p, len2 = s_len;
    {
        const int* pp = paths + (size_t)p2 * max_len;
        float acc = 0.f;
        for (int j = 0; j < len2; ++j)
            acc += emb[(size_t)pp[j] * 256 + tid];
        out[2 + tid] = acc / (float)len2;
    }
    if (tid == 0) { out[0] = (float)p2; out[1] = s_logprob; }
}

extern "C" void kernel_launch(void* const* d_in, const int* in_sizes, int n_in,
                              void* d_out, int out_size, void* d_ws, size_t ws_size,
                              hipStream_t stream) {
    const float* emb       = (const float*)d_in[0];   // [n_edges, 256]
    const int*   paths     = (const int*)  d_in[1];   // [n_paths, max_len]
    const int*   path_lens = (const int*)  d_in[2];   // [n_paths]
    const int*   path_mask = (const int*)  d_in[3];   // [n_paths]
    const float* W         = (const float*)d_in[4];   // [256]
    const float* b         = (const float*)d_in[5];   // [1]

    int hidden  = in_sizes[4];                 // 256
    int n_edges = in_sizes[0] / hidden;        // 100000
    int n_paths = in_sizes[2];                 // 20000
    int max_len = in_sizes[1] / n_paths;       // 16

    float* s      = (float*)d_ws;              // 400 KB
    float* logits = s + n_edges;               // 80 KB
    int*   counter = (int*)(logits + n_paths);

    // counter must be zeroed every call (d_ws re-poisoned to 0xAA)
    hipMemsetAsync(counter, 0, sizeof(int), stream);

    // K1: one wave per edge row -> 4 waves/block
    int blocks1 = (n_edges * 64 + 255) / 256;
    k_edge_dot<<<blocks1, 256, 0, stream>>>(emb, W, s, n_edges);

    // K2 + finalize fused (last block does argmax/logsumexp/z[p])
    int blocks2 = (n_paths + 255) / 256;
    k_logits_final<<<blocks2, 256, 0, stream>>>(s, paths, path_lens, path_mask,
                                                b, emb, logits, counter,
                                                (float*)d_out, n_paths, max_len);
}

// Round 4
// 167.082 us; speedup vs baseline: 1.0916x; 1.0916x over previous
//
#include <hip/hip_runtime.h>
#include <math.h>

#define NEG_INF -1e9f

// K1: s[e] = dot(edge_emb[e], W)   -- one wave (64 lanes) per 256-float row.
// Memory-floor kernel: reads emb exactly once (102.4 MB), coalesced float4.
__global__ __launch_bounds__(256) void k_edge_dot(
    const float* __restrict__ emb, const float* __restrict__ W,
    float* __restrict__ s, int n_edges)
{
    int wave = (blockIdx.x * (int)blockDim.x + (int)threadIdx.x) >> 6;
    int lane = threadIdx.x & 63;
    if (wave >= n_edges) return;
    const float4 e = ((const float4*)emb)[wave * 64 + lane];
    const float4 w = ((const float4*)W)[lane];
    float d = e.x * w.x + e.y * w.y + e.z * w.z + e.w * w.w;
#pragma unroll
    for (int off = 32; off; off >>= 1) d += __shfl_down(d, off, 64);
    if (lane == 0) s[wave] = d;
}

// K2: logits[p] = (sum_{j<len} s[paths[p][j]]) / len + b, masked to -1e9.
// Mask short-circuit first (no gathers for ~50% masked paths), then
// int4 path loads + 16 independent branchless gathers (full ILP).
__global__ __launch_bounds__(256) void k_logits16(
    const float* __restrict__ s, const int* __restrict__ paths,
    const int* __restrict__ path_lens, const int* __restrict__ path_mask,
    const float* __restrict__ b, float* __restrict__ logits, int n_paths)
{
    int p = blockIdx.x * (int)blockDim.x + (int)threadIdx.x;
    if (p >= n_paths) return;
    if (path_mask[p] == 0) { logits[p] = NEG_INF; return; }
    int len = path_lens[p] + 1;                 // 1..16
    const int4* pp4 = (const int4*)(paths + (size_t)p * 16);
    int4 a0 = pp4[0], a1 = pp4[1], a2 = pp4[2], a3 = pp4[3];
    int idx[16] = { a0.x, a0.y, a0.z, a0.w, a1.x, a1.y, a1.z, a1.w,
                    a2.x, a2.y, a2.z, a2.w, a3.x, a3.y, a3.z, a3.w };
    float acc = 0.f;
#pragma unroll
    for (int j = 0; j < 16; ++j) {
        float v = s[idx[j]];                    // always in-bounds
        acc += (j < len) ? v : 0.f;
    }
    logits[p] = acc / (float)len + b[0];
}

// Generic fallback (max_len != 16)
__global__ __launch_bounds__(256) void k_logits_gen(
    const float* __restrict__ s, const int* __restrict__ paths,
    const int* __restrict__ path_lens, const int* __restrict__ path_mask,
    const float* __restrict__ b, float* __restrict__ logits,
    int n_paths, int max_len)
{
    int p = blockIdx.x * (int)blockDim.x + (int)threadIdx.x;
    if (p >= n_paths) return;
    if (path_mask[p] == 0) { logits[p] = NEG_INF; return; }
    int len = path_lens[p] + 1;
    const int* pp = paths + (size_t)p * max_len;
    float acc = 0.f;
    for (int j = 0; j < len; ++j) acc += s[pp[j]];
    logits[p] = acc / (float)len + b[0];
}

// K3: single block. argmax (first-occurrence tie-break), logsumexp,
// then materialize z[p] and write [p, logprob, z[0..255]].
__global__ __launch_bounds__(1024) void k_final(
    const float* __restrict__ logits, const float* __restrict__ emb,
    const int* __restrict__ paths, const int* __restrict__ path_lens,
    float* __restrict__ out, int n_paths, int max_len)
{
    __shared__ float sv[16];
    __shared__ int   si[16];
    __shared__ float ssum[16];
    __shared__ int   s_p, s_len;
    __shared__ float s_max, s_logprob;

    int tid = threadIdx.x, lane = tid & 63, wv = tid >> 6;
    int n4 = n_paths >> 2;
    const float4* l4 = (const float4*)logits;

    // pass 1: block-wide argmax with first-index tie-break (float4 sweep)
    float bv = -INFINITY; int bi = 0x7fffffff;
    for (int i = tid; i < n4; i += 1024) {
        float4 v = l4[i];
        int base = i << 2;
        if (v.x > bv) { bv = v.x; bi = base; }
        if (v.y > bv) { bv = v.y; bi = base + 1; }
        if (v.z > bv) { bv = v.z; bi = base + 2; }
        if (v.w > bv) { bv = v.w; bi = base + 3; }
    }
    for (int i = (n4 << 2) + tid; i < n_paths; i += 1024) {  // tail
        float v = logits[i];
        if (v > bv) { bv = v; bi = i; }
    }
#pragma unroll
    for (int off = 32; off; off >>= 1) {
        float ov = __shfl_down(bv, off, 64);
        int   oi = __shfl_down(bi, off, 64);
        if (ov > bv || (ov == bv && oi < bi)) { bv = ov; bi = oi; }
    }
    if (lane == 0) { sv[wv] = bv; si[wv] = bi; }
    __syncthreads();
    if (tid == 0) {
        float mv = sv[0]; int mi = si[0];
        for (int w = 1; w < 16; ++w)
            if (sv[w] > mv || (sv[w] == mv && si[w] < mi)) { mv = sv[w]; mi = si[w]; }
        s_max = mv; s_p = mi; s_len = path_lens[mi] + 1;
    }
    __syncthreads();
    float mx = s_max;

    // pass 2: sum exp(logits - max);  logp[argmax] = -log(sumexp)
    float se = 0.f;
    for (int i = tid; i < n4; i += 1024) {
        float4 v = l4[i];
        se += expf(v.x - mx) + expf(v.y - mx) + expf(v.z - mx) + expf(v.w - mx);
    }
    for (int i = (n4 << 2) + tid; i < n_paths; i += 1024)
        se += expf(logits[i] - mx);
#pragma unroll
    for (int off = 32; off; off >>= 1) se += __shfl_down(se, off, 64);
    if (lane == 0) ssum[wv] = se;
    __syncthreads();
    if (tid == 0) {
        float t = 0.f;
        for (int w = 0; w < 16; ++w) t += ssum[w];
        s_logprob = -logf(t);
    }
    __syncthreads();

    // z[p]: 256 threads, one per hidden dim; sum over valid edges of winner
    int p = s_p, len = s_len;
    if (tid < 256) {
        const int* pp = paths + (size_t)p * max_len;
        float acc = 0.f;
        for (int j = 0; j < len; ++j)
            acc += emb[(size_t)pp[j] * 256 + tid];
        out[2 + tid] = acc / (float)len;
    }
    if (tid == 0) { out[0] = (float)p; out[1] = s_logprob; }
}

extern "C" void kernel_launch(void* const* d_in, const int* in_sizes, int n_in,
                              void* d_out, int out_size, void* d_ws, size_t ws_size,
                              hipStream_t stream) {
    const float* emb       = (const float*)d_in[0];   // [n_edges, 256]
    const int*   paths     = (const int*)  d_in[1];   // [n_paths, max_len]
    const int*   path_lens = (const int*)  d_in[2];   // [n_paths]
    const int*   path_mask = (const int*)  d_in[3];   // [n_paths]
    const float* W         = (const float*)d_in[4];   // [256]
    const float* b         = (const float*)d_in[5];   // [1]

    int hidden  = in_sizes[4];                 // 256
    int n_edges = in_sizes[0] / hidden;        // 100000
    int n_paths = in_sizes[2];                 // 20000
    int max_len = in_sizes[1] / n_paths;       // 16

    float* s      = (float*)d_ws;              // 400 KB
    float* logits = s + n_edges;               // 80 KB

    // K1: one wave per edge row -> 4 waves/block
    int blocks1 = (n_edges * 64 + 255) / 256;
    k_edge_dot<<<blocks1, 256, 0, stream>>>(emb, W, s, n_edges);

    // K2: one thread per path
    int blocks2 = (n_paths + 255) / 256;
    if (max_len == 16)
        k_logits16<<<blocks2, 256, 0, stream>>>(s, paths, path_lens, path_mask,
                                                b, logits, n_paths);
    else
        k_logits_gen<<<blocks2, 256, 0, stream>>>(s, paths, path_lens, path_mask,
                                                  b, logits, n_paths, max_len);

    // K3: single block finalization
    k_final<<<1, 1024, 0, stream>>>(logits, emb, paths, path_lens,
                                    (float*)d_out, n_paths, max_len);
}